// Round 4
// baseline (15100.655 us; speedup 1.0000x reference)
//
#include <hip/hip_runtime.h>
#include <hip/hip_cooperative_groups.h>

namespace cg = cooperative_groups;

typedef float v2f __attribute__((ext_vector_type(2)));

#define B_  64
#define T_  128
#define E_  512
#define HH_ 256
#define HN_ 1024
#define D_  4
#define V_  10000
#define NR_ (T_*D_)   // 512 chained updates
#define NWG_ 256

// ---- dynamic LDS layout (float offsets). Row strides ≡ 8 (mod 32 banks):
// wave-wide reads at float4 index (u*16+kk) give start banks (8*jj+4*kk)%32 →
// 8 lanes per 4-bank slot, 1KB distinct data per ds_read_b128. ----
#define WH_STR   1032
#define WI_STR   520
#define WS_STR   264
#define WH_OFF   0            // Wh:  8 rows x 1032  (rows w*4+jj, +HN)
#define WU_OFF   8256         // Wup: 4 rows x 264   (rows w*4+jj)
#define WI_OFF   9312         // Wi:  8 rows x 520   (rows w*4+jj, +HN)
#define WHH_OFF  13472        // Whh: 32 rows x 264  (rows ch0+rr, +HH)
#define WIH_OFF  21920        // Wih: 32 rows x 520
#define LDS_FLOATS 38560      // 154240 B -> 1 WG/CU (16 waves = 4/SIMD)

// ---- device-coherent (agent-scope, sc0 sc1 -> served at L3 coherence point)
// state accessors. R4: replaces per-round fence(agent) pairs, whose L1/L2
// inv + dirty-L2 writeback walks were the prime suspect for the ~10us/round
// fixed cost. Read-only inputs (weights/embed/xx/biases) stay plain-cached
// and now remain warm in L1/L2 across all 512 rounds. ----
__device__ __forceinline__ v2f ld2_dev(const float* p) {
    unsigned long long a = __hip_atomic_load((const unsigned long long*)p,
                                             __ATOMIC_RELAXED, __HIP_MEMORY_SCOPE_AGENT);
    return __builtin_bit_cast(v2f, a);
}
__device__ __forceinline__ float4 ld4_dev(const float* p) {
    v2f lo = ld2_dev(p);
    v2f hi = ld2_dev(p + 2);
    return make_float4(lo.x, lo.y, hi.x, hi.y);
}
__device__ __forceinline__ float ld1_dev(const float* p) {
    unsigned v = __hip_atomic_load((const unsigned*)p,
                                   __ATOMIC_RELAXED, __HIP_MEMORY_SCOPE_AGENT);
    return __builtin_bit_cast(float, v);
}
__device__ __forceinline__ void st1_dev(float* p, float v) {
    __hip_atomic_store((unsigned*)p, __builtin_bit_cast(unsigned, v),
                       __ATOMIC_RELAXED, __HIP_MEMORY_SCOPE_AGENT);
}

// ---- 16-lane-row sum via DPP (VALU pipe, NOT the shared LDS pipe) ----
__device__ __forceinline__ float row16_sum(float x) {
    int v = __builtin_bit_cast(int, x);
    x += __builtin_bit_cast(float, __builtin_amdgcn_update_dpp(0, v, 0xB1, 0xF, 0xF, true));
    v = __builtin_bit_cast(int, x);
    x += __builtin_bit_cast(float, __builtin_amdgcn_update_dpp(0, v, 0x4E, 0xF, 0xF, true));
    v = __builtin_bit_cast(int, x);
    x += __builtin_bit_cast(float, __builtin_amdgcn_update_dpp(0, v, 0x124, 0xF, 0xF, true));
    v = __builtin_bit_cast(int, x);
    x += __builtin_bit_cast(float, __builtin_amdgcn_update_dpp(0, v, 0x128, 0xF, 0xF, true));
    return x;
}

__device__ __forceinline__ float sel4(int s, float a, float b, float c, float d) {
    return s == 0 ? a : (s == 1 ? b : (s == 2 ? c : d));
}

// -------------------------------------------------------------------------
// Two-phase flag barrier, FENCE-FREE (R4). All mutable state moves via
// agent-scope (sc0 sc1) ops that are always served at the L3 coherence
// point, so no cache invalidate/writeback walks are needed. Ordering:
// __syncthreads drains each wave's vmcnt (stores committed at L3) before
// the flag store; VMEM issues in program order per wave, and the poll
// branch + syncthreads order the next round's loads after gen observation.
// -------------------------------------------------------------------------
__device__ __forceinline__ void flag_barrier(int* __restrict__ flags,
                                             int* __restrict__ gen,
                                             int w, int tau, int target)
{
    __syncthreads();                       // all waves' stores drained (vmcnt 0)
    if (tau == 0) {
        asm volatile("s_waitcnt vmcnt(0)" ::: "memory");
        __hip_atomic_store(&flags[w * 16], target, __ATOMIC_RELAXED,
                           __HIP_MEMORY_SCOPE_AGENT);
    }
    if (w == 0) {
        if (tau < NWG_) {
            while (__hip_atomic_load(&flags[tau * 16], __ATOMIC_RELAXED,
                                     __HIP_MEMORY_SCOPE_AGENT) < target) {
                __builtin_amdgcn_s_sleep(1);
            }
        }
        __syncthreads();                   // all flags seen
        if (tau == 0)
            __hip_atomic_store(gen, target, __ATOMIC_RELAXED,
                               __HIP_MEMORY_SCOPE_AGENT);
    } else if (tau == 0) {
        while (__hip_atomic_load(gen, __ATOMIC_RELAXED,
                                 __HIP_MEMORY_SCOPE_AGENT) < target) {
            __builtin_amdgcn_s_sleep(1);
        }
    }
    __builtin_amdgcn_fence(__ATOMIC_ACQUIRE, "workgroup");  // compiler barrier, no L2 walk
    __syncthreads();                       // every thread past the poll
}

// -------------------------------------------------------------------------
// Persistent cooperative recurrence. 256 WGs x 1024 thr, 513 rounds.
// Wave bq handles b-quad {bq*4..bq*4+3}; lane = (jj = lane>>4, kk = lane&15).
// Weights in LDS (wave-wide conflict-floor reads); state via L3-coherent
// atomics; K-reduce (16-way over kk) via DPP on the VALU pipe.
// -------------------------------------------------------------------------
__global__ __launch_bounds__(1024, 1) void recur_kernel(
    const int*   __restrict__ xx,
    const float* __restrict__ embed,
    const float* __restrict__ Whh, const float* __restrict__ bhh,
    const float* __restrict__ Wih, const float* __restrict__ bih,
    const float* __restrict__ Wh,  const float* __restrict__ bh,
    const float* __restrict__ Wi,  const float* __restrict__ bi,
    const float* __restrict__ Wup, const float* __restrict__ bup,
    float* __restrict__ sH,   // [2][B_][HH_]
    float* __restrict__ sN,   // [2][B_][HN_]
    float* __restrict__ hOut, // [B_*T_][HN_]
    int*   __restrict__ flags,
    int*   __restrict__ gen)
{
    extern __shared__ float lds[];
    cg::grid_group grid = cg::this_grid();
    const int w   = blockIdx.x;
    const int tau = threadIdx.x;
    const int gid = w * 1024 + tau;
    const int ch0 = (w & 15) * 16;

    // ---------------- stage per-WG weights into LDS (once) ----------------
    for (int idx = tau; idx < 2048; idx += 1024) {         // Wh 8x1024
        int r = idx >> 8, kq = idx & 255;
        int grow = w*4 + (r & 3) + (r >> 2) * HN_;
        *(float4*)&lds[WH_OFF + r*WH_STR + kq*4] =
            *(const float4*)(Wh + (size_t)grow * HN_ + kq*4);
    }
    if (tau < 256) {                                       // Wup 4x256
        int r = tau >> 6, kq = tau & 63;
        *(float4*)&lds[WU_OFF + r*WS_STR + kq*4] =
            *(const float4*)(Wup + (size_t)(w*4 + r) * HH_ + kq*4);
    }
    if (tau < 1024) {                                      // Wi 8x512
        int r = tau >> 7, kq = tau & 127;
        int grow = w*4 + (r & 3) + (r >> 2) * HN_;
        *(float4*)&lds[WI_OFF + r*WI_STR + kq*4] =
            *(const float4*)(Wi + (size_t)grow * E_ + kq*4);
    }
    for (int idx = tau; idx < 2048; idx += 1024) {         // Whh 32x256
        int r = idx >> 6, kq = idx & 63;
        int grow = ch0 + (r & 15) + (r >> 4) * HH_;
        *(float4*)&lds[WHH_OFF + r*WS_STR + kq*4] =
            *(const float4*)(Whh + (size_t)grow * HH_ + kq*4);
    }
    for (int idx = tau; idx < 4096; idx += 1024) {         // Wih 32x512
        int r = idx >> 7, kq = idx & 127;
        int grow = ch0 + (r & 15) + (r >> 4) * HH_;
        *(float4*)&lds[WIH_OFF + r*WI_STR + kq*4] =
            *(const float4*)(Wih + (size_t)grow * E_ + kq*4);
    }

    // init states (ws is poisoned 0xAA): sH parity 0, sN parity 1.
    // Plain stores; the single cg grid.sync below release-fences them to
    // the coherence point, so the round-0 coherent loads see them.
    if (gid < B_ * HH_) sH[gid] = 0.f;
    if (gid < B_ * HN_) sN[B_ * HN_ + gid] = 0.f;
    if (tau == 0) flags[w * 16] = 0;
    if (w == 0 && tau == 0) *gen = 0;
    __syncthreads();
    grid.sync();   // single cg sync: inits + staging inputs coherent

    // ---------------- per-thread constants ----------------
    const int lane = tau & 63;
    const int bq   = tau >> 6;        // wave id = b-quad (b = bq*4+bb)
    const int kk   = lane & 15;       // K-split 16 (DPP-row dimension)
    const int jj   = lane >> 4;       // output col within WG's 4 / bH index

    // sN side
    const int j = w * 4 + jj;
    const float bh1 = bh[j],  bh2 = bh[j + HN_];
    const float bi1 = bi[j],  bi2 = bi[j + HN_];
    const float bupj = bup[j];
    const float* wrow1 = lds + WH_OFF + jj * WH_STR;        // Wh[j]
    const float* wrow2 = lds + WH_OFF + (4 + jj) * WH_STR;  // Wh[j+HN]
    const float* urow  = lds + WU_OFF + jj * WS_STR;        // Wup[j]
    const float* yrow1 = lds + WI_OFF + jj * WI_STR;        // Wi[j]
    const float* yrow2 = lds + WI_OFF + (4 + jj) * WI_STR;  // Wi[j+HN]

    // sH side: wave bq owns channel ch; lane row jj -> batch bH
    const int ch = ch0 + bq;
    const int bH = (w >> 4) * 4 + jj;
    const float bhh1 = bhh[ch], bhh2 = bhh[ch + HH_];
    const float bih1 = bih[ch], bih2 = bih[ch + HH_];
    const float* qrow1 = lds + WHH_OFF + bq * WS_STR;         // Whh[ch]
    const float* qrow2 = lds + WHH_OFF + (16 + bq) * WS_STR;  // Whh[ch+HH]
    const float* prow1 = lds + WIH_OFF + bq * WI_STR;         // Wih[ch]
    const float* prow2 = lds + WIH_OFF + (16 + bq) * WI_STR;  // Wih[ch+HH]

    for (int r = 0; r <= NR_; ++r) {
        const int p = r & 1;
        const float* sNp = sN + p * (B_ * HN_);
        const float* sHp = sH + p * (B_ * HH_);
        float* sNn = sN + (1 - p) * (B_ * HN_);
        float* sHn = sH + (1 - p) * (B_ * HH_);

        // ---------------- sN chain: update s = r-1 ----------------
        if (r >= 1) {
            const int s = r - 1;
            const int t = s >> 2;
            const int i = s & 3;

            const float* sb0 = sNp + (bq * 4 + 0) * HN_;
            const float* sb1 = sNp + (bq * 4 + 1) * HN_;
            const float* sb2 = sNp + (bq * 4 + 2) * HN_;
            const float* sb3 = sNp + (bq * 4 + 3) * HN_;

            v2f A1[4], A2[4], Z[4];
            #pragma unroll
            for (int bb = 0; bb < 4; ++bb) { A1[bb] = (v2f){0.f,0.f}; A2[bb] = (v2f){0.f,0.f}; Z[bb] = (v2f){0.f,0.f}; }

            #pragma unroll
            for (int u = 0; u < 16; ++u) {
                const int fi = (u * 16 + kk) * 4;
                float4 w1 = *(const float4*)(wrow1 + fi);
                float4 w2 = *(const float4*)(wrow2 + fi);
                float4 s0 = ld4_dev(sb0 + fi);
                float4 s1 = ld4_dev(sb1 + fi);
                float4 s2 = ld4_dev(sb2 + fi);
                float4 s3 = ld4_dev(sb3 + fi);
                v2f w1l = {w1.x, w1.y}, w1h = {w1.z, w1.w};
                v2f w2l = {w2.x, w2.y}, w2h = {w2.z, w2.w};
                v2f a;
                a = (v2f){s0.x, s0.y}; A1[0] += a * w1l; A2[0] += a * w2l;
                a = (v2f){s0.z, s0.w}; A1[0] += a * w1h; A2[0] += a * w2h;
                a = (v2f){s1.x, s1.y}; A1[1] += a * w1l; A2[1] += a * w2l;
                a = (v2f){s1.z, s1.w}; A1[1] += a * w1h; A2[1] += a * w2h;
                a = (v2f){s2.x, s2.y}; A1[2] += a * w1l; A2[2] += a * w2l;
                a = (v2f){s2.z, s2.w}; A1[2] += a * w1h; A2[2] += a * w2h;
                a = (v2f){s3.x, s3.y}; A1[3] += a * w1l; A2[3] += a * w2l;
                a = (v2f){s3.z, s3.w}; A1[3] += a * w1h; A2[3] += a * w2h;
            }

            if (i == 0) {   // + xt @ Wi.T (biases added post-reduce)
                const int t0 = xx[(bq * 4 + 0) * T_ + t];
                const int t1 = xx[(bq * 4 + 1) * T_ + t];
                const int t2 = xx[(bq * 4 + 2) * T_ + t];
                const int t3 = xx[(bq * 4 + 3) * T_ + t];
                const float* e0 = embed + (size_t)t0 * E_;
                const float* e1 = embed + (size_t)t1 * E_;
                const float* e2 = embed + (size_t)t2 * E_;
                const float* e3 = embed + (size_t)t3 * E_;
                #pragma unroll
                for (int u = 0; u < 8; ++u) {
                    const int fi = (u * 16 + kk) * 4;
                    float4 y1 = *(const float4*)(yrow1 + fi);
                    float4 y2 = *(const float4*)(yrow2 + fi);
                    float4 v0 = *(const float4*)(e0 + fi);
                    float4 v1 = *(const float4*)(e1 + fi);
                    float4 v2 = *(const float4*)(e2 + fi);
                    float4 v3 = *(const float4*)(e3 + fi);
                    v2f y1l = {y1.x, y1.y}, y1h = {y1.z, y1.w};
                    v2f y2l = {y2.x, y2.y}, y2h = {y2.z, y2.w};
                    v2f a;
                    a = (v2f){v0.x, v0.y}; A1[0] += a * y1l; A2[0] += a * y2l;
                    a = (v2f){v0.z, v0.w}; A1[0] += a * y1h; A2[0] += a * y2h;
                    a = (v2f){v1.x, v1.y}; A1[1] += a * y1l; A2[1] += a * y2l;
                    a = (v2f){v1.z, v1.w}; A1[1] += a * y1h; A2[1] += a * y2h;
                    a = (v2f){v2.x, v2.y}; A1[2] += a * y1l; A2[2] += a * y2l;
                    a = (v2f){v2.z, v2.w}; A1[2] += a * y1h; A2[2] += a * y2h;
                    a = (v2f){v3.x, v3.y}; A1[3] += a * y1l; A2[3] += a * y2l;
                    a = (v2f){v3.z, v3.w}; A1[3] += a * y1h; A2[3] += a * y2h;
                }
            }

            // z = sH_new @ Wup.T (sHp IS post-update-(s) sH)
            {
                const float* hb0 = sHp + (bq * 4 + 0) * HH_;
                const float* hb1 = sHp + (bq * 4 + 1) * HH_;
                const float* hb2 = sHp + (bq * 4 + 2) * HH_;
                const float* hb3 = sHp + (bq * 4 + 3) * HH_;
                #pragma unroll
                for (int u = 0; u < 4; ++u) {
                    const int fi = (u * 16 + kk) * 4;
                    float4 uw = *(const float4*)(urow + fi);
                    float4 h0 = ld4_dev(hb0 + fi);
                    float4 h1 = ld4_dev(hb1 + fi);
                    float4 h2 = ld4_dev(hb2 + fi);
                    float4 h3 = ld4_dev(hb3 + fi);
                    v2f ul = {uw.x, uw.y}, uh = {uw.z, uw.w};
                    v2f a;
                    a = (v2f){h0.x, h0.y}; Z[0] += a * ul;
                    a = (v2f){h0.z, h0.w}; Z[0] += a * uh;
                    a = (v2f){h1.x, h1.y}; Z[1] += a * ul;
                    a = (v2f){h1.z, h1.w}; Z[1] += a * uh;
                    a = (v2f){h2.x, h2.y}; Z[2] += a * ul;
                    a = (v2f){h2.z, h2.w}; Z[2] += a * uh;
                    a = (v2f){h3.x, h3.y}; Z[3] += a * ul;
                    a = (v2f){h3.z, h3.w}; Z[3] += a * uh;
                }
            }

            // K-reduce over kk (16 lanes within DPP row) — VALU pipe only
            float a1r0 = row16_sum(A1[0].x + A1[0].y);
            float a1r1 = row16_sum(A1[1].x + A1[1].y);
            float a1r2 = row16_sum(A1[2].x + A1[2].y);
            float a1r3 = row16_sum(A1[3].x + A1[3].y);
            float a2r0 = row16_sum(A2[0].x + A2[0].y);
            float a2r1 = row16_sum(A2[1].x + A2[1].y);
            float a2r2 = row16_sum(A2[2].x + A2[2].y);
            float a2r3 = row16_sum(A2[3].x + A2[3].y);
            float zr0  = row16_sum(Z[0].x + Z[0].y);
            float zr1  = row16_sum(Z[1].x + Z[1].y);
            float zr2  = row16_sum(Z[2].x + Z[2].y);
            float zr3  = row16_sum(Z[3].x + Z[3].y);

            const int bsel = bq * 4 + (kk & 3);
            const float ov = ld1_dev(sNp + bsel * HN_ + j);   // issued early

            if (kk < 4) {
                float g1 = sel4(kk, a1r0, a1r1, a1r2, a1r3) + bh1;
                float g2 = sel4(kk, a2r0, a2r1, a2r2, a2r3) + bh2;
                if (i == 0) { g1 += bi1; g2 += bi2; }
                const float zv  = sel4(kk, zr0, zr1, zr2, zr3) + bupj;
                const float g_h = g1 * zv;
                const float g_t = g2 * zv;
                const float sg  = 1.f / (1.f + expf(-g_t));
                const float nv  = tanhf(g_h) * sg + ov * (1.f - sg);
                st1_dev(sNn + bsel * HN_ + j, nv);
                if (i == D_ - 1) hOut[(size_t)(bsel * T_ + t) * HN_ + j] = nv;
            }
        }

        // ---------------- sH chain: update r ----------------
        if (r < NR_) {
            const int t = r >> 2;
            const int i = r & 3;
            v2f a1v = {0.f, 0.f}, a2v = {0.f, 0.f};
            const float* shb = sHp + bH * HH_;
            #pragma unroll
            for (int uu = 0; uu < 4; ++uu) {
                const int fi = (((jj + uu) & 3) * 16 + kk) * 4;  // g-staggered: wave-wide distinct
                float4 q1 = *(const float4*)(qrow1 + fi);
                float4 q2 = *(const float4*)(qrow2 + fi);
                float4 sv = ld4_dev(shb + fi);
                v2f q1l = {q1.x, q1.y}, q1h = {q1.z, q1.w};
                v2f q2l = {q2.x, q2.y}, q2h = {q2.z, q2.w};
                v2f a;
                a = (v2f){sv.x, sv.y}; a1v += a * q1l; a2v += a * q2l;
                a = (v2f){sv.z, sv.w}; a1v += a * q1h; a2v += a * q2h;
            }
            if (i == 0) {   // + xt @ Wih.T
                const int tok = xx[bH * T_ + t];
                const float* eb = embed + (size_t)tok * E_;
                #pragma unroll
                for (int uu = 0; uu < 4; ++uu) {
                    const int fi = (((jj + uu) & 3) * 16 + kk) * 4;
                    float4 p1a = *(const float4*)(prow1 + fi);
                    float4 p1b = *(const float4*)(prow1 + fi + 256);
                    float4 p2a = *(const float4*)(prow2 + fi);
                    float4 p2b = *(const float4*)(prow2 + fi + 256);
                    float4 ea  = *(const float4*)(eb + fi);
                    float4 eb2 = *(const float4*)(eb + fi + 256);
                    v2f a;
                    a = (v2f){ea.x, ea.y};  a1v += a * (v2f){p1a.x, p1a.y}; a2v += a * (v2f){p2a.x, p2a.y};
                    a = (v2f){ea.z, ea.w};  a1v += a * (v2f){p1a.z, p1a.w}; a2v += a * (v2f){p2a.z, p2a.w};
                    a = (v2f){eb2.x, eb2.y}; a1v += a * (v2f){p1b.x, p1b.y}; a2v += a * (v2f){p2b.x, p2b.y};
                    a = (v2f){eb2.z, eb2.w}; a1v += a * (v2f){p1b.z, p1b.w}; a2v += a * (v2f){p2b.z, p2b.w};
                }
            }
            float a1 = row16_sum(a1v.x + a1v.y);
            float a2 = row16_sum(a2v.x + a2v.y);
            const float ovh = ld1_dev(sHp + bH * HH_ + ch);   // issued early
            if (kk == 0) {
                a1 += bhh1; a2 += bhh2;
                if (i == 0) { a1 += bih1; a2 += bih2; }
                const float sg = 1.f / (1.f + expf(-a2));
                st1_dev(sHn + bH * HH_ + ch, tanhf(a1) * sg + ovh * (1.f - sg));
            }
        }

        flag_barrier(flags, gen, w, tau, r + 1);
    }
}

// -------------------------------------------------------------------------
// Output projection: out[bt, v] = h[bt, :] . Wout[v, :] + bout[v]
// M=8192, N=10000, K=1024. 64x64 tile, 256 threads, 4x4 acc/thread.
// R4: tiles padded [32][68] — the old stride-64 staging put all 8 lanes of
// a row in one bank (5.8e8 conflict cycles); stride 68 spreads them while
// keeping float4 alignment (68*4B ≡ 16B-aligned rows).
// -------------------------------------------------------------------------
__global__ __launch_bounds__(256) void out_gemm(
    const float* __restrict__ hb, const float* __restrict__ Wout,
    const float* __restrict__ bout, float* __restrict__ op)
{
    __shared__ float Ht[32][68];  // [k][m] (+4 pad)
    __shared__ float Wt[32][68];  // [k][n] (+4 pad)
    const int tau = threadIdx.x;
    const int tx  = tau & 15;
    const int ty  = tau >> 4;
    const int m0  = blockIdx.x * 64;
    const int n0  = blockIdx.y * 64;
    float acc[4][4] = {{0.f}};

    for (int k0 = 0; k0 < HN_; k0 += 32) {
        #pragma unroll
        for (int l = 0; l < 2; ++l) {
            const int f   = tau + l * 256;   // 0..511
            const int row = f >> 3;          // 64 rows
            const int kq  = (f & 7) * 4;     // 8 float4 per row
            float4 hv = *(const float4*)(hb + (size_t)(m0 + row) * HN_ + k0 + kq);
            Ht[kq + 0][row] = hv.x; Ht[kq + 1][row] = hv.y;
            Ht[kq + 2][row] = hv.z; Ht[kq + 3][row] = hv.w;
            const int vr = n0 + row;
            float4 wv = (vr < V_) ? *(const float4*)(Wout + (size_t)vr * HN_ + k0 + kq)
                                  : make_float4(0.f, 0.f, 0.f, 0.f);
            Wt[kq + 0][row] = wv.x; Wt[kq + 1][row] = wv.y;
            Wt[kq + 2][row] = wv.z; Wt[kq + 3][row] = wv.w;
        }
        __syncthreads();
        #pragma unroll
        for (int kq = 0; kq < 32; ++kq) {
            float4 av = *(const float4*)(&Ht[kq][ty * 4]);
            float4 bv = *(const float4*)(&Wt[kq][tx * 4]);
            acc[0][0] += av.x * bv.x; acc[0][1] += av.x * bv.y;
            acc[0][2] += av.x * bv.z; acc[0][3] += av.x * bv.w;
            acc[1][0] += av.y * bv.x; acc[1][1] += av.y * bv.y;
            acc[1][2] += av.y * bv.z; acc[1][3] += av.y * bv.w;
            acc[2][0] += av.z * bv.x; acc[2][1] += av.z * bv.y;
            acc[2][2] += av.z * bv.z; acc[2][3] += av.z * bv.w;
            acc[3][0] += av.w * bv.x; acc[3][1] += av.w * bv.y;
            acc[3][2] += av.w * bv.z; acc[3][3] += av.w * bv.w;
        }
        __syncthreads();
    }

    #pragma unroll
    for (int ii = 0; ii < 4; ++ii) {
        const int m = m0 + ty * 4 + ii;
        #pragma unroll
        for (int jq = 0; jq < 4; ++jq) {
            const int v = n0 + tx * 4 + jq;
            if (v < V_) op[(size_t)m * V_ + v] = acc[ii][jq] + bout[v];
        }
    }
}

extern "C" void kernel_launch(void* const* d_in, const int* in_sizes, int n_in,
                              void* d_out, int out_size, void* d_ws, size_t ws_size,
                              hipStream_t stream) {
    const int*   xx    = (const int*)  d_in[0];
    const float* embed = (const float*)d_in[1];
    const float* Whh   = (const float*)d_in[2];
    const float* bhh   = (const float*)d_in[3];
    const float* Wih   = (const float*)d_in[4];
    const float* bih   = (const float*)d_in[5];
    const float* Wh    = (const float*)d_in[6];
    const float* bh    = (const float*)d_in[7];
    const float* Wi    = (const float*)d_in[8];
    const float* bi    = (const float*)d_in[9];
    const float* Wup   = (const float*)d_in[10];
    const float* bup   = (const float*)d_in[11];
    const float* Wout  = (const float*)d_in[12];
    const float* bout  = (const float*)d_in[13];

    float* ws   = (float*)d_ws;
    float* hbuf = ws;                                   // 8192*1024 floats
    float* sHb  = hbuf + (size_t)B_ * T_ * HN_;         // 2*64*256
    float* sNb  = sHb + 2 * B_ * HH_;                   // 2*64*1024
    int*   flg  = (int*)(sNb + 2 * B_ * HN_);           // 256 padded lines
    int*   gen  = flg + NWG_ * 16;                      // own line

    void* args[] = { (void*)&xx, (void*)&embed, (void*)&Whh, (void*)&bhh,
                     (void*)&Wih, (void*)&bih, (void*)&Wh, (void*)&bh,
                     (void*)&Wi, (void*)&bi, (void*)&Wup, (void*)&bup,
                     (void*)&sHb, (void*)&sNb, (void*)&hbuf,
                     (void*)&flg, (void*)&gen };
    hipLaunchCooperativeKernel(reinterpret_cast<void*>(recur_kernel),
                               dim3(256), dim3(1024), args,
                               (size_t)(LDS_FLOATS * 4), stream);

    out_gemm<<<dim3(T_ * B_ / 64, (V_ + 63) / 64), 256, 0, stream>>>(
        hbuf, Wout, bout, (float*)d_out);
}